// Round 6
// baseline (201.179 us; speedup 1.0000x reference)
//
#include <hip/hip_runtime.h>

typedef _Float16 f16;
typedef __attribute__((ext_vector_type(2))) _Float16 f16x2;
typedef __attribute__((ext_vector_type(4))) _Float16 f16x4;
typedef __attribute__((ext_vector_type(8))) _Float16 f16x8;
typedef __attribute__((ext_vector_type(4))) float f32x4;

#define D_MODEL 1024
#define SEQ 2048
#define NBATCH 4
#define NROWS (NBATCH * SEQ)  // 8192

// ---------------------------------------------------------------- utilities
__device__ __forceinline__ void gload16(const void* g, void* l) {
  __builtin_amdgcn_global_load_lds(
      (__attribute__((address_space(1))) void*)(void*)g,
      (__attribute__((address_space(3))) void*)l, 16, 0, 0);
}

#define BARF                                   \
  do {                                         \
    asm volatile("" ::: "memory");             \
    __builtin_amdgcn_s_barrier();              \
    asm volatile("" ::: "memory");             \
  } while (0)
#define LGK asm volatile("s_waitcnt lgkmcnt(0)" ::: "memory")
#define LGK8 asm volatile("s_waitcnt lgkmcnt(8)" ::: "memory")
#define PRIO1 __builtin_amdgcn_s_setprio(1)
#define PRIO0 __builtin_amdgcn_s_setprio(0)

// ------------------------------------------------------- 8-phase GEMM core
// BM=256, BN in {256,128}, BK=64, 512 threads (8 waves = 2M x 4N), f16 MFMA
// 16x16x32, fp32 acc. See R5 comment block; unchanged except the partial
// lgkmcnt(8) in the 12-read phases (P1/P5), per the m201 template.

#define STAGE_A(D, H)                                        \
  {                                                          \
    f16* d_ = lds + ((D) * 2 + (H)) * 8192 + t * 8;          \
    gload16((H) ? aP2 : aP0, d_);                            \
    gload16((H) ? aP3 : aP1, d_ + 4096);                     \
  }
#define STAGE_B(D, H)                                        \
  {                                                          \
    if constexpr (BN == 256) {                               \
      f16* d_ = lds + 32768 + ((D) * 2 + (H)) * 8192 + t * 8;\
      gload16((H) ? bP2 : bP0, d_);                          \
      gload16((H) ? bP3 : bP1, d_ + 4096);                   \
    } else {                                                 \
      f16* d_ = lds + 32768 + (D) * 8192 + t * 8;            \
      gload16(bP0, d_);                                      \
      gload16(bP1, d_ + 4096);                               \
    }                                                        \
  }
#define ADVA                                                 \
  {                                                          \
    if (ka < NT - 1) {                                       \
      ka++;                                                  \
      aP0 += stepA; aP1 += stepA; aP2 += stepA; aP3 += stepA;\
    }                                                        \
  }
#define ADVB                                                 \
  {                                                          \
    if (kb < NT - 1) {                                       \
      kb++;                                                  \
      bP0 += stepB; bP1 += stepB;                            \
      if constexpr (BN == 256) { bP2 += stepB; bP3 += stepB; } \
    }                                                        \
  }
#define VMC_STEADY                                           \
  {                                                          \
    if constexpr (BN == 256) {                               \
      asm volatile("s_waitcnt vmcnt(4)" ::: "memory");       \
    } else {                                                 \
      asm volatile("s_waitcnt vmcnt(2)" ::: "memory");       \
    }                                                        \
  }
#define RD_A(D, MH)                                          \
  _Pragma("unroll") for (int mi = 0; mi < 4; ++mi)           \
  _Pragma("unroll") for (int kh = 0; kh < 2; ++kh) {         \
    const int rr = (MH) * 64 + mi * 16 + fr;                 \
    fa[mi][kh] = *(const f16x8*)(lds + ((D) * 2 + wm) * 8192 \
        + rr * 64 + (((g0 + kh * 4) ^ (rr & 7)) << 3));      \
  }
#define RD_B(D, NH)                                          \
  _Pragma("unroll") for (int j = 0; j < NJ; ++j)             \
  _Pragma("unroll") for (int kh = 0; kh < 2; ++kh) {         \
    int rbr, base;                                           \
    if constexpr (BN == 256) {                               \
      rbr = (wn & 1) * 64 + fr * 4 + (NH) * 2 + j;           \
      base = 32768 + ((D) * 2 + (wn >> 1)) * 8192;           \
    } else {                                                 \
      rbr = wn * 32 + fr * 2 + (NH);                         \
      base = 32768 + (D) * 8192;                             \
    }                                                        \
    fb[NH][j][kh] = *(const f16x8*)(lds + base + rbr * 64 +  \
        (((g0 + kh * 4) ^ ((rbr >> 2) & 7)) << 3));          \
  }
#define MFMA_Q(MH, NH)                                       \
  _Pragma("unroll") for (int mi = 0; mi < 4; ++mi)           \
  _Pragma("unroll") for (int j = 0; j < NJ; ++j)             \
  _Pragma("unroll") for (int kh = 0; kh < 2; ++kh)           \
    acc[((MH) * 4 + mi) * 2 * NJ + (NH) * NJ + j] =          \
        __builtin_amdgcn_mfma_f32_16x16x32_f16(              \
            fa[mi][kh], fb[NH][j][kh],                       \
            acc[((MH) * 4 + mi) * 2 * NJ + (NH) * NJ + j], 0, 0, 0);

template <int BN>
__device__ __forceinline__ void gemm8p(
    const f16* aP0, const f16* aP1, const f16* aP2, const f16* aP3,
    const f16* bP0, const f16* bP1, const f16* bP2, const f16* bP3,
    int stepA, int stepB, int NT, f16* lds, f32x4* acc)
{
  constexpr int NJ = BN / 128;
  const int t = threadIdx.x, l = t & 63;
  const int w = t >> 6, wm = w >> 2, wn = w & 3;
  const int fr = l & 15, g0 = l >> 4;
  f16x8 fa[4][2], fb[2][NJ][2];
#pragma unroll
  for (int i = 0; i < 8 * 2 * NJ; ++i) acc[i] = f32x4{0.f, 0.f, 0.f, 0.f};
  int ka = 0, kb = 0;
  (void)bP2; (void)bP3;

  // prologue: T0.A -> dbuf0, T0.B -> dbuf0, T1.B -> dbuf1
  STAGE_A(0, 0); STAGE_A(0, 1); ADVA;
  if constexpr (BN == 256) { STAGE_B(0, 0); STAGE_B(0, 1); }
  else { STAGE_B(0, 0); }
  ADVB;
  if constexpr (BN == 256) { STAGE_B(1, 0); STAGE_B(1, 1); }
  else { STAGE_B(1, 0); }
  ADVB;
  VMC_STEADY;   // T0 fully landed; T1.B in flight
  BARF;

#pragma unroll 1
  for (int it = 0; it < NT / 2; ++it) {
    // ---- P1: T0 quadrant (0,0); stage T1.A0
    RD_A(0, 0); RD_B(0, 0);
    STAGE_A(1, 0);
    LGK8;
    BARF; LGK;
    PRIO1; MFMA_Q(0, 0); PRIO0;
    BARF;
    // ---- P2: (0,1); stage T1.A1
    RD_B(0, 1);
    STAGE_A(1, 1); ADVA;
    BARF; LGK;
    PRIO1; MFMA_Q(0, 1); PRIO0;
    BARF;
    // ---- P3: (1,0); stage T2.B0
    RD_A(0, 1);
    STAGE_B(0, 0);
    if constexpr (BN == 128) ADVB;
    BARF; LGK;
    PRIO1; MFMA_Q(1, 0); PRIO0;
    BARF;
    // ---- P4: (1,1); stage T2.B1; counted vmcnt -> T1 landed
    if constexpr (BN == 256) { STAGE_B(0, 1); ADVB; }
    VMC_STEADY;
    BARF;
    PRIO1; MFMA_Q(1, 1); PRIO0;
    BARF;
    // ---- P5: T1 quadrant (0,0); stage T2.A0
    RD_A(1, 0); RD_B(1, 0);
    STAGE_A(0, 0);
    LGK8;
    BARF; LGK;
    PRIO1; MFMA_Q(0, 0); PRIO0;
    BARF;
    // ---- P6: (0,1); stage T2.A1
    RD_B(1, 1);
    STAGE_A(0, 1); ADVA;
    BARF; LGK;
    PRIO1; MFMA_Q(0, 1); PRIO0;
    BARF;
    // ---- P7: (1,0); stage T3.B0
    RD_A(1, 1);
    STAGE_B(1, 0);
    if constexpr (BN == 128) ADVB;
    BARF; LGK;
    PRIO1; MFMA_Q(1, 0); PRIO0;
    BARF;
    // ---- P8: (1,1); stage T3.B1; counted vmcnt -> T2 landed
    if constexpr (BN == 256) { STAGE_B(1, 1); ADVB; }
    VMC_STEADY;
    BARF;
    PRIO1; MFMA_Q(1, 1); PRIO0;
    BARF;
  }
}

// ------------------ GEMM1: QKV, BN=256 (m201 geometry), grid 384, XCD-swz
__global__ __launch_bounds__(512, 2) void k_qkv3(
    const f16* __restrict__ srch, const f16* __restrict__ wt,
    f16* __restrict__ qp, f16* __restrict__ kp, f16* __restrict__ vp)
{
  __shared__ f16 lds[65536];
  const int t = threadIdx.x, l = t & 63;
  const int w = t >> 6, wm = w >> 2, wn = w & 3;
  const int fr = l & 15, g0 = l >> 4, c = t & 7;
  // bijective XCD swizzle: 384 blocks = 8 XCDs x 48
  const int bid = blockIdx.x;
  const int sb = (bid & 7) * 48 + (bid >> 3);
  const int bx = sb & 31, by = sb >> 5;    // bx: M-tile 0..31, by: N-tile 0..11
  const int z = by >> 2, cb = by & 3;
  const f16 *aP[4], *bP[4];
#pragma unroll
  for (int i = 0; i < 4; ++i) {
    const int rl = i * 64 + (t >> 3);
    aP[i] = srch + (size_t)(bx * 256 + rl) * 1024 + ((c ^ (rl & 7)) << 3);
    bP[i] = wt + ((size_t)z << 20) + (size_t)(cb * 256 + rl) * 1024 +
            ((c ^ ((rl >> 2) & 7)) << 3);
  }
  f32x4 acc[32];
  gemm8p<256>(aP[0], aP[1], aP[2], aP[3], bP[0], bP[1], bP[2], bP[3],
              64, 64, 16, lds, acc);
  f16* dst = (z == 0) ? qp : (z == 1 ? kp : vp);
  const int col = cb * 256 + wn * 64 + fr * 4;
#pragma unroll
  for (int mi = 0; mi < 8; ++mi)
#pragma unroll
    for (int q = 0; q < 4; ++q) {
      const int row = bx * 256 + wm * 128 + mi * 16 + g0 * 4 + q;
      f16x4 o = {(f16)acc[mi * 4 + 0][q], (f16)acc[mi * 4 + 1][q],
                 (f16)acc[mi * 4 + 2][q], (f16)acc[mi * 4 + 3][q]};
      *(f16x4*)(dst + (size_t)row * 1024 + col) = o;
    }
}

// --------------------------- GEMM2: scores = Qt*Kt^T/32, f16 out (gathered)
__global__ __launch_bounds__(512, 2) void k_scores(
    const f16* __restrict__ qp, const f16* __restrict__ kp,
    f16* __restrict__ abf)
{
  __shared__ f16 lds[65536];
  const int t = threadIdx.x, l = t & 63;
  const int w = t >> 6, wm = w >> 2, wn = w & 3;
  const int fr = l & 15, g0 = l >> 4, c = t & 7;
  const int b = blockIdx.z;
  const f16* qb = qp + ((size_t)b << 21);
  const f16* kb = kp + ((size_t)b << 21);
  const f16 *aP[4], *bP[4];
#pragma unroll
  for (int i = 0; i < 4; ++i) {
    const int rl = i * 64 + (t >> 3);
    const int spA = blockIdx.x * 256 + rl;
    aP[i] = qb + (size_t)((spA & 127) << 4) * 1024 + ((spA >> 7) << 6) +
            ((c ^ (rl & 7)) << 3);
    const int spB = blockIdx.y * 256 + rl;
    bP[i] = kb + (size_t)((spB & 127) << 4) * 1024 + ((spB >> 7) << 6) +
            ((c ^ ((rl >> 2) & 7)) << 3);
  }
  f32x4 acc[32];
  gemm8p<256>(aP[0], aP[1], aP[2], aP[3], bP[0], bP[1], bP[2], bP[3],
              1024, 1024, 16, lds, acc);
  f16* Cb = abf + ((size_t)b << 22);
  const int col = blockIdx.y * 256 + wn * 64 + fr * 4;
#pragma unroll
  for (int mi = 0; mi < 8; ++mi)
#pragma unroll
    for (int q = 0; q < 4; ++q) {
      const int row = blockIdx.x * 256 + wm * 128 + mi * 16 + g0 * 4 + q;
      f16x4 o = {(f16)(acc[mi * 4 + 0][q] * 0.03125f),
                 (f16)(acc[mi * 4 + 1][q] * 0.03125f),
                 (f16)(acc[mi * 4 + 2][q] * 0.03125f),
                 (f16)(acc[mi * 4 + 3][q] * 0.03125f)};
      *(f16x4*)(Cb + (size_t)row * 2048 + col) = o;
    }
}

// ------------------------------------- GEMM3: att = a * Vt, f16 out, BN=128
__global__ __launch_bounds__(512, 2) void k_att(
    const f16* __restrict__ abf, const f16* __restrict__ vtT,
    f16* __restrict__ attb)
{
  __shared__ f16 lds[49152];
  const int t = threadIdx.x, l = t & 63;
  const int w = t >> 6, wm = w >> 2, wn = w & 3;
  const int fr = l & 15, g0 = l >> 4, c = t & 7;
  const int b = blockIdx.z;
  const f16* ab = abf + ((size_t)b << 22);
  const f16* vb = vtT + ((size_t)b << 21);
  const f16 *aP[4], *bP[2];
#pragma unroll
  for (int i = 0; i < 4; ++i) {
    const int rl = i * 64 + (t >> 3);
    aP[i] = ab + (size_t)(blockIdx.x * 256 + rl) * 2048 + ((c ^ (rl & 7)) << 3);
  }
#pragma unroll
  for (int i = 0; i < 2; ++i) {
    const int rl = i * 64 + (t >> 3);
    bP[i] = vb + (size_t)(blockIdx.y * 128 + rl) * 2048 +
            ((c ^ ((rl >> 2) & 7)) << 3);
  }
  f32x4 acc[16];
  gemm8p<128>(aP[0], aP[1], aP[2], aP[3], bP[0], bP[1], bP[0], bP[0],
              64, 64, 32, lds, acc);
  f16* Cb = attb + ((size_t)b << 21);
  const int col = blockIdx.y * 128 + wn * 32 + fr * 2;
#pragma unroll
  for (int mi = 0; mi < 8; ++mi)
#pragma unroll
    for (int q = 0; q < 4; ++q) {
      const int row = blockIdx.x * 256 + wm * 128 + mi * 16 + g0 * 4 + q;
      f16x2 o = {(f16)acc[mi * 2 + 0][q], (f16)acc[mi * 2 + 1][q]};
      *(f16x2*)(Cb + (size_t)row * 1024 + col) = o;
    }
}

// ----------------- merged prep: src cast (blocks 0..4095) + W^T cast (rest)
__global__ __launch_bounds__(256) void k_prep(
    const float* __restrict__ src, const float* __restrict__ w0,
    const float* __restrict__ w1, const float* __restrict__ w2,
    f16* __restrict__ srch, f16* __restrict__ wt)
{
  const int b = blockIdx.x, t = threadIdx.x;
  if (b < 4096) {
    const size_t i = (size_t)b * 256 + t;
    const float4* p = (const float4*)src;
    float4 v0 = p[2 * i], v1 = p[2 * i + 1];
    f16x8 o;
    o[0] = (f16)v0.x; o[1] = (f16)v0.y; o[2] = (f16)v0.z; o[3] = (f16)v0.w;
    o[4] = (f16)v1.x; o[5] = (f16)v1.y; o[6] = (f16)v1.z; o[7] = (f16)v1.w;
    *(f16x8*)(srch + 8 * i) = o;
    return;
  }
  const int id = b - 4096;            // 0..767
  const int z = id >> 8, rem = id & 255;
  const int bx = rem & 15, by = rem >> 4;
  const float* in = (z == 0) ? w0 : (z == 1 ? w1 : w2);
  f16* o = wt + ((size_t)z << 20);
  __shared__ f16 tile[64][65];
  const int rr = t >> 4, c4 = (t & 15) * 4;
  const int r0 = bx * 64, c0 = by * 64;
#pragma unroll
  for (int i = 0; i < 4; ++i) {
    float4 f = *(const float4*)(in + (size_t)(r0 + rr + 16 * i) * 1024 + c0 + c4);
    tile[rr + 16 * i][c4 + 0] = (f16)f.x;
    tile[rr + 16 * i][c4 + 1] = (f16)f.y;
    tile[rr + 16 * i][c4 + 2] = (f16)f.z;
    tile[rr + 16 * i][c4 + 3] = (f16)f.w;
  }
  __syncthreads();
#pragma unroll
  for (int i = 0; i < 4; ++i) {
    const int n = c0 + rr + 16 * i;
    f16* dst = o + (size_t)n * 1024 + r0 + c4;
    dst[0] = tile[c4 + 0][rr + 16 * i];
    dst[1] = tile[c4 + 1][rr + 16 * i];
    dst[2] = tile[c4 + 2][rr + 16 * i];
    dst[3] = tile[c4 + 3][rr + 16 * i];
  }
}

// ---------- merged: softmax rows (blocks 0..8191) + V scramble-T (rest)
__global__ __launch_bounds__(256) void k_softscr(
    float* __restrict__ out, f16* __restrict__ abf,
    const f16* __restrict__ vp, f16* __restrict__ vtT)
{
  __shared__ f16 shm[64][68];
  const int t = threadIdx.x;
  if (blockIdx.x < 8192) {
    float* red = (float*)&shm[0][0];
    const size_t base = (size_t)blockIdx.x * 2048;
    const int lane = t & 63, w = t >> 6;
    f16x8 v = *(const f16x8*)(abf + base + (size_t)t * 8);
    float x[8];
#pragma unroll
    for (int j = 0; j < 8; ++j) x[j] = (float)v[j];
    float m = fmaxf(fmaxf(fmaxf(x[0], x[1]), fmaxf(x[2], x[3])),
                    fmaxf(fmaxf(x[4], x[5]), fmaxf(x[6], x[7])));
#pragma unroll
    for (int off = 1; off < 64; off <<= 1) m = fmaxf(m, __shfl_xor(m, off));
    if (lane == 0) red[w] = m;
    __syncthreads();
    m = fmaxf(fmaxf(red[0], red[1]), fmaxf(red[2], red[3]));
    float s = 0.f;
#pragma unroll
    for (int j = 0; j < 8; ++j) { x[j] = __expf(x[j] - m); s += x[j]; }
#pragma unroll
    for (int off = 1; off < 64; off <<= 1) s += __shfl_xor(s, off);
    if (lane == 0) red[4 + w] = s;
    __syncthreads();
    s = red[4] + red[5] + red[6] + red[7];
    const float inv = 1.0f / s;
#pragma unroll
    for (int j = 0; j < 8; ++j) x[j] *= inv;
    float4 o0 = {x[0], x[1], x[2], x[3]}, o1 = {x[4], x[5], x[6], x[7]};
    ((float4*)(out + base))[2 * t] = o0;
    ((float4*)(out + base))[2 * t + 1] = o1;
    f16x8 ov;
#pragma unroll
    for (int j = 0; j < 8; ++j) ov[j] = (f16)x[j];
    *(f16x8*)(abf + base + (size_t)t * 8) = ov;
    return;
  }
  // ---- scramble-transpose of V
  const int id = blockIdx.x - 8192;           // 0..2047
  const int sx = id & 31, sy = (id >> 5) & 15, bz = id >> 9;
  const int sp0 = sx * 64, dp0 = sy * 64;
  const int d6 = dp0 >> 6;
  const int jb = (sp0 >> 7) << 6;
  const int sbase = sp0 & 127;
  const f16* srcv = vp + ((size_t)bz << 21);
  f16* dstv = vtT + ((size_t)bz << 21);
#pragma unroll
  for (int p = 0; p < 2; ++p) {
    const int u = p * 32 + (t >> 3);
    const int s = ((sbase + u) << 4) | d6;
    const int cc = (t & 7) << 3;
    f16x8 v = *(const f16x8*)(srcv + (size_t)s * 1024 + jb + cc);
    *(f16x4*)&shm[u][cc]     = f16x4{v[0], v[1], v[2], v[3]};
    *(f16x4*)&shm[u][cc + 4] = f16x4{v[4], v[5], v[6], v[7]};
  }
  __syncthreads();
#pragma unroll
  for (int p = 0; p < 2; ++p) {
    const int cc = p * 32 + (t >> 3);
    const int v0 = (t & 7) << 3;
    f16x8 o;
#pragma unroll
    for (int j = 0; j < 8; ++j) o[j] = shm[v0 + j][cc];
    *(f16x8*)(dstv + (size_t)(dp0 + cc) * 2048 + sp0 + v0) = o;
  }
}

// --------------------------------------------- fused LN1 + add + LN2
__global__ __launch_bounds__(256) void k_ln(
    const f16* __restrict__ attb, const float* __restrict__ src,
    const float* __restrict__ w1, const float* __restrict__ b1,
    const float* __restrict__ w2, const float* __restrict__ b2,
    float* __restrict__ out)
{
  const size_t base = (size_t)blockIdx.x * 1024;
  const int t = threadIdx.x, lane = t & 63, w = t >> 6;
  f16x4 a4 = ((const f16x4*)(attb + base))[t];
  float ax = (float)a4[0], ay = (float)a4[1], az = (float)a4[2], aw = (float)a4[3];
  float s = ax + ay + az + aw;
  float s2 = ax * ax + ay * ay + az * az + aw * aw;
#pragma unroll
  for (int off = 1; off < 64; off <<= 1) {
    s += __shfl_xor(s, off);
    s2 += __shfl_xor(s2, off);
  }
  __shared__ float red[16];
  if (lane == 0) { red[w] = s; red[4 + w] = s2; }
  __syncthreads();
  s = red[0] + red[1] + red[2] + red[3];
  s2 = red[4] + red[5] + red[6] + red[7];
  float mu = s * (1.0f / 1024.0f);
  float var = s2 * (1.0f / 1024.0f) - mu * mu;
  float rs = rsqrtf(var + 1e-5f);
  float4 W1 = ((const float4*)w1)[t], B1 = ((const float4*)b1)[t];
  float4 sv = ((const float4*)(src + base))[t];
  float y0 = sv.x + (ax - mu) * rs * W1.x + B1.x;
  float y1 = sv.y + (ay - mu) * rs * W1.y + B1.y;
  float y2 = sv.z + (az - mu) * rs * W1.z + B1.z;
  float y3 = sv.w + (aw - mu) * rs * W1.w + B1.w;
  s = y0 + y1 + y2 + y3;
  s2 = y0 * y0 + y1 * y1 + y2 * y2 + y3 * y3;
#pragma unroll
  for (int off = 1; off < 64; off <<= 1) {
    s += __shfl_xor(s, off);
    s2 += __shfl_xor(s2, off);
  }
  if (lane == 0) { red[8 + w] = s; red[12 + w] = s2; }
  __syncthreads();
  s = red[8] + red[9] + red[10] + red[11];
  s2 = red[12] + red[13] + red[14] + red[15];
  mu = s * (1.0f / 1024.0f);
  var = s2 * (1.0f / 1024.0f) - mu * mu;
  rs = rsqrtf(var + 1e-5f);
  float4 W2 = ((const float4*)w2)[t], B2 = ((const float4*)b2)[t];
  float4 o;
  o.x = (y0 - mu) * rs * W2.x + B2.x;
  o.y = (y1 - mu) * rs * W2.y + B2.y;
  o.z = (y2 - mu) * rs * W2.z + B2.z;
  o.w = (y3 - mu) * rs * W2.w + B2.w;
  ((float4*)(out + base))[t] = o;
}

// ---------------------------------------------------------------- launch
extern "C" void kernel_launch(void* const* d_in, const int* in_sizes, int n_in,
                              void* d_out, int out_size, void* d_ws, size_t ws_size,
                              hipStream_t stream) {
  const float* src = (const float*)d_in[0];
  const float* Wq  = (const float*)d_in[1];
  const float* Wk  = (const float*)d_in[2];
  const float* Wv  = (const float*)d_in[3];
  const float* l1w = (const float*)d_in[4];
  const float* l1b = (const float*)d_in[5];
  const float* l2w = (const float*)d_in[6];
  const float* l2b = (const float*)d_in[7];
  float* Xout = (float*)d_out;
  float* Aout = Xout + (size_t)NROWS * D_MODEL;

  // workspace layout (134 MB, non-overlapping)
  char* ws = (char*)d_ws;
  f16* srch = (f16*)ws;                       // 16 MB (8192x1024)
  f16* wt   = (f16*)(ws + (16u << 20));       //  6 MB (3072x1024, W^T)
  f16* qp   = (f16*)(ws + (22u << 20));       // 16 MB
  f16* kp   = (f16*)(ws + (38u << 20));       // 16 MB
  f16* vp   = (f16*)(ws + (54u << 20));       // 16 MB
  f16* vtT  = (f16*)(ws + (70u << 20));       // 16 MB (B,D,S scrambled-T)
  f16* abf  = (f16*)(ws + (86u << 20));       // 32 MB (B,S,S scores->a f16)
  f16* attb = (f16*)(ws + (118u << 20));      // 16 MB (B,S,D f16)

  k_prep<<<4864, 256, 0, stream>>>(src, Wq, Wk, Wv, srch, wt);
  k_qkv3<<<384, 512, 0, stream>>>(srch, wt, qp, kp, vp);
  k_scores<<<dim3(8, 8, 4), 512, 0, stream>>>(qp, kp, abf);
  k_softscr<<<8192 + 2048, 256, 0, stream>>>(Aout, abf, vp, vtT);
  k_att<<<dim3(8, 8, 4), 512, 0, stream>>>(abf, vtT, attb);
  k_ln<<<NROWS, 256, 0, stream>>>(attb, src, l1w, l1b, l2w, l2b, Xout);
}